// Round 20
// baseline (271.164 us; speedup 1.0000x reference)
//
#include <hip/hip_runtime.h>
#include <hip/hip_bf16.h>
#include <hip/hip_fp16.h>
#include <cstdint>

#define N_NODES 50000
#define N_EDGES 800000

typedef _Float16 half8_t __attribute__((ext_vector_type(8)));
typedef float f32x4 __attribute__((ext_vector_type(4)));

// ---------------------------------------------------------------------------
// Prepack W (fp32 [DIN][DOUT]) into fp16 B-fragment order for 16x16x32 MFMA,
// plus an extra 16-col tile holding Wal/War (el/er as GEMM columns).
template<int DIN, int DOUT, int F>
__device__ __forceinline__ void prepack_body(
    const float* __restrict__ W, const float* __restrict__ al,
    const float* __restrict__ ar, __half* __restrict__ Wp, int f)
{
    constexpr int NKS = DIN / 32;
    constexpr int NT  = DOUT / 16;
    constexpr int H   = DOUT / F;
    int lane = f & 63;
    int ks   = (f >> 6) % NKS;
    int nt   = (f >> 6) / NKS;
    int kbase = ks * 32 + (lane >> 4) * 8;
    int n = lane & 15;
    __half h[8];
    if (nt < NT) {
#pragma unroll
        for (int j = 0; j < 8; ++j)
            h[j] = __float2half(W[(size_t)(kbase + j) * DOUT + nt * 16 + n]);
    } else {
#pragma unroll
        for (int j = 0; j < 8; ++j) {
            float s = 0.f;
            if (n < H) {
                for (int ff = 0; ff < F; ++ff)
                    s += W[(size_t)(kbase + j) * DOUT + n * F + ff] * al[n * F + ff];
            } else if (n < 2 * H) {
                int hh = n - H;
                for (int ff = 0; ff < F; ++ff)
                    s += W[(size_t)(kbase + j) * DOUT + hh * F + ff] * ar[hh * F + ff];
            }
            h[j] = __float2half(s);
        }
    }
    *reinterpret_cast<uint4*>(&Wp[(size_t)f * 8]) = *reinterpret_cast<uint4*>(h);
}

// prepack all 3 layers (regions 4608 | 2304 | 1280) PLUS deg zeroing (fused).
__global__ void prepack_zero(
    const float* __restrict__ W0, const float* __restrict__ al0, const float* __restrict__ ar0,
    const float* __restrict__ W1, const float* __restrict__ al1, const float* __restrict__ ar1,
    const float* __restrict__ W2, const float* __restrict__ al2, const float* __restrict__ ar2,
    __half* __restrict__ Wp0, __half* __restrict__ Wp1, __half* __restrict__ Wp2,
    int* __restrict__ deg)
{
    int f = blockIdx.x * blockDim.x + threadIdx.x;
    if (f < 4608)       prepack_body<256, 128, 16>(W0, al0, ar0, Wp0, f);
    else if (f < 6912)  prepack_body<128, 128, 16>(W1, al1, ar1, Wp1, f - 4608);
    else if (f < 8192)  prepack_body<128, 64, 64>(W2, al2, ar2, Wp2, f - 6912);
    else {
        int i = f - 8192;
        if (i < N_NODES) deg[i] = 0;
    }
}

// ---------------------------------------------------------------------------
// feat = X @ W via fp16 MFMA (fp32 accum), el/er as extra output columns.
// Burst A-load: ALL DIN/8 per-lane loads issued back-to-back (16 in flight
// for L0), then convert, then MFMA. R19 PMC showed the 1-deep prefetch left
// X streaming latency-bound at 1.47 TB/s.
template<int DIN, int DOUT, int F, typename XT>
__device__ __forceinline__ void gemm_body(
    int bid, const XT* __restrict__ X, const __half* __restrict__ Wp,
    __half* __restrict__ feat, float* __restrict__ el, float* __restrict__ er, int N)
{
    constexpr int NKS = DIN / 32;
    constexpr int NT  = DOUT / 16;
    constexpr int NTT = NT + 1;         // + el/er tile
    constexpr int H   = DOUT / F;

    const int wid  = threadIdx.x >> 6;
    const int lane = threadIdx.x & 63;
    const int row0 = bid * 64 + wid * 16;
    const int m    = lane & 15;
    const int kg   = lane >> 4;

    const int rowa = min(row0 + m, N - 1);
    const XT* Xr = X + (size_t)rowa * DIN + kg * 8;

    f32x4 acc[NTT];
#pragma unroll
    for (int i = 0; i < NTT; ++i) acc[i] = (f32x4){0.f, 0.f, 0.f, 0.f};

    // ---- burst-load the whole per-lane A segment, then convert ----
    half8_t a[NKS];
    if constexpr (sizeof(XT) == 4) {
        float4 xf[NKS][2];
#pragma unroll
        for (int ks = 0; ks < NKS; ++ks) {
            xf[ks][0] = *reinterpret_cast<const float4*>(Xr + ks * 32);
            xf[ks][1] = *reinterpret_cast<const float4*>(Xr + ks * 32 + 4);
        }
#pragma unroll
        for (int ks = 0; ks < NKS; ++ks) {
            a[ks][0] = (_Float16)xf[ks][0].x; a[ks][1] = (_Float16)xf[ks][0].y;
            a[ks][2] = (_Float16)xf[ks][0].z; a[ks][3] = (_Float16)xf[ks][0].w;
            a[ks][4] = (_Float16)xf[ks][1].x; a[ks][5] = (_Float16)xf[ks][1].y;
            a[ks][6] = (_Float16)xf[ks][1].z; a[ks][7] = (_Float16)xf[ks][1].w;
        }
    } else {
#pragma unroll
        for (int ks = 0; ks < NKS; ++ks)
            a[ks] = *reinterpret_cast<const half8_t*>(Xr + ks * 32);
    }

#pragma unroll
    for (int ks = 0; ks < NKS; ++ks) {
#pragma unroll
        for (int nt = 0; nt < NTT; ++nt) {
            const half8_t b = *reinterpret_cast<const half8_t*>(
                Wp + ((size_t)(nt * NKS + ks) * 64 + lane) * 8);
            acc[nt] = __builtin_amdgcn_mfma_f32_16x16x32_f16(a[ks], b, acc[nt], 0, 0, 0);
        }
    }

    // ---- store: C/D layout col=lane&15, row=(lane>>4)*4+reg ----
    const int q = lane >> 4;
#pragma unroll
    for (int reg = 0; reg < 4; ++reg) {
        const int row = row0 + 4 * q + reg;
        if (row < N) {
#pragma unroll
            for (int nt = 0; nt < NT; ++nt)
                feat[(size_t)row * DOUT + nt * 16 + m] = __float2half(acc[nt][reg]);
            const float v = acc[NT][reg];
            if (m < H)          el[(size_t)row * H + m] = v;
            else if (m < 2 * H) er[(size_t)row * H + (m - H)] = v;
        }
    }
}

template<int DIN, int DOUT, int F, typename XT>
__global__ __launch_bounds__(256) void gemm_attn_mfma(
    const XT* __restrict__ X, const __half* __restrict__ Wp,
    __half* __restrict__ feat, float* __restrict__ el, float* __restrict__ er, int N)
{
    gemm_body<DIN, DOUT, F, XT>(blockIdx.x, X, Wp, feat, el, er, N);
}

// ---------------------------------------------------------------------------
// dst-range-partitioned CSR fill body (R16-proven XCD-affine scatter).
__device__ __forceinline__ void build_body(
    int bid, const int* __restrict__ src, const int* __restrict__ dst,
    int* __restrict__ cursor, int* __restrict__ csr_src)
{
    constexpr int RNG = N_NODES / 8;        // 6250
    constexpr int SS  = N_EDGES / 100;      // 8000 edges per slice
    const int g  = bid & 7;
    const int s  = bid >> 3;                // 0..99
    const int lo = g * RNG;
    const int e0 = s * SS;

    for (int q = threadIdx.x; q < SS / 4; q += 256) {
        const int4 d = *reinterpret_cast<const int4*>(&dst[e0 + 4 * q]);
#pragma unroll
        for (int k = 0; k < 4; ++k) {
            const int dv = (k == 0) ? d.x : (k == 1) ? d.y : (k == 2) ? d.z : d.w;
            const unsigned r = (unsigned)(dv - lo);
            if (r < (unsigned)RNG) {
                int sv = src[e0 + 4 * q + k];
                int p = atomicAdd(&cursor[dv], 1);
                csr_src[p] = sv;
            }
        }
    }
}

// Fused: layer-0 MFMA gemm (blocks 0..781) || CSR fill (blocks 784..1583).
__global__ __launch_bounds__(256) void gemm0_csr(
    const float* __restrict__ X, const __half* __restrict__ Wp0,
    __half* __restrict__ feat, float* __restrict__ el, float* __restrict__ er, int N,
    const int* __restrict__ src, const int* __restrict__ dst,
    int* __restrict__ cursor, int* __restrict__ csr_src)
{
    if (blockIdx.x < 784) {
        if (blockIdx.x < 782)
            gemm_body<256, 128, 16, float>(blockIdx.x, X, Wp0, feat, el, er, N);
    } else {
        build_body(blockIdx.x - 784, src, dst, cursor, csr_src);
    }
}

// ---------------------------------------------------------------------------
// dst-range-partitioned histogram (R16/R18-proven).
__global__ __launch_bounds__(256) void hist_deg_part(
    const int* __restrict__ dst, int* __restrict__ deg)
{
    constexpr int RNG = N_NODES / 8;
    constexpr int SS  = N_EDGES / 100;
    const int g  = blockIdx.x & 7;
    const int s  = blockIdx.x >> 3;
    const int lo = g * RNG;
    const int e0 = s * SS;
    for (int q = threadIdx.x; q < SS / 4; q += 256) {
        const int4 d = *reinterpret_cast<const int4*>(&dst[e0 + 4 * q]);
#pragma unroll
        for (int k = 0; k < 4; ++k) {
            const int dv = (k == 0) ? d.x : (k == 1) ? d.y : (k == 2) ? d.z : d.w;
            if ((unsigned)(dv - lo) < (unsigned)RNG) atomicAdd(&deg[dv], 1);
        }
    }
}

// Multi-block scan, 3 stages.
__global__ __launch_bounds__(1024) void scan_partials(
    const int* __restrict__ deg, int* __restrict__ btot, int n)
{
    __shared__ int wsum[16];
    const int tid = threadIdx.x;
    const int lane = tid & 63, wid = tid >> 6;
    int i = blockIdx.x * 1024 + tid;
    int v = (i < n) ? deg[i] : 0;
#pragma unroll
    for (int off = 1; off < 64; off <<= 1) v += __shfl_xor(v, off);
    if (lane == 0) wsum[wid] = v;
    __syncthreads();
    if (tid < 16) {
        int w = wsum[tid];
#pragma unroll
        for (int off = 1; off < 16; off <<= 1) w += __shfl_xor(w, off, 16);
        if (tid == 0) btot[blockIdx.x] = w;
    }
}

__global__ void scan_btot(int* __restrict__ btot, int nb)
{
    int tid = threadIdx.x;          // one wave, nb <= 64
    int v = (tid < nb) ? btot[tid] : 0;
    int x = v;
#pragma unroll
    for (int off = 1; off < 64; off <<= 1) {
        int t = __shfl_up(x, off);
        if (tid >= off) x += t;
    }
    if (tid < nb) btot[tid] = x - v;    // exclusive
}

// Writes offs AND initializes cursor = offs.
__global__ __launch_bounds__(1024) void scan_final(
    const int* __restrict__ deg, const int* __restrict__ bcar,
    int* __restrict__ offs, int* __restrict__ cursor, int n)
{
    __shared__ int wtot[16], wincl[16];
    const int tid = threadIdx.x;
    const int lane = tid & 63, wid = tid >> 6;
    int i = blockIdx.x * 1024 + tid;
    int v = (i < n) ? deg[i] : 0;
    int x = v;
#pragma unroll
    for (int off = 1; off < 64; off <<= 1) {
        int t = __shfl_up(x, off);
        if (lane >= off) x += t;
    }
    if (lane == 63) wtot[wid] = x;
    __syncthreads();
    if (tid < 16) {
        int wx = wtot[tid];
#pragma unroll
        for (int off = 1; off < 16; off <<= 1) {
            int t = __shfl_up(wx, off, 16);
            if (tid >= off) wx += t;
        }
        wincl[tid] = wx;
    }
    __syncthreads();
    int waveExcl = (wid == 0) ? 0 : wincl[wid - 1];
    if (i < n) {
        int o = bcar[blockIdx.x] + waveExcl + (x - v);
        offs[i] = o;
        cursor[i] = o;
    }
    if (i == 0) offs[n] = N_EDGES;
}

// ---------------------------------------------------------------------------
// Fused softmax + aggregation per dst node. One wave per node. fp16 feat.
template<int H, int F, bool ACT, typename OT>
__global__ __launch_bounds__(256) void node_flash_agg(
    const int* __restrict__ offs, const int* __restrict__ csr_src,
    const float* __restrict__ el, const float* __restrict__ er,
    const __half* __restrict__ feat, const float* __restrict__ bias,
    OT* __restrict__ out, int N)
{
    constexpr int D = H * F;
    constexpr int CPT = D / 64;             // 2 or 1
    constexpr int EPC = 64 / H;             // 8 or 64
    constexpr int MAXCH = (H == 8) ? 4 : 1; // fast path: deg<=32 / 64
    constexpr int SB = 8;
    constexpr int NB = MAXCH * EPC / SB;    // feat batches (4 or 8)

    const int wid = threadIdx.x >> 6;
    const int lane = threadIdx.x & 63;
    const int n = blockIdx.x * 4 + wid;
    if (n >= N) return;

    const int beg = offs[n];
    const int deg = offs[n + 1] - beg;

    const int comp0 = CPT * lane;
    const int myhead = comp0 / F;

    auto store_out = [&](float a0, float a1) {
        if constexpr (CPT == 2) {
            if constexpr (sizeof(OT) == 2) {
                *reinterpret_cast<__half2*>(&out[(size_t)n * D + comp0]) =
                    __floats2half2_rn(a0, a1);
            } else {
                *reinterpret_cast<float2*>(&out[(size_t)n * D + comp0]) =
                    make_float2(a0, a1);
            }
        } else {
            out[(size_t)n * D + comp0] = (OT)a0;
        }
    };

    if (deg == 0) {
        float v0 = bias[comp0], v1 = (CPT == 2) ? bias[comp0 + 1] : 0.f;
        if (ACT) {
            v0 = (v0 > 0.f) ? v0 : (__expf(v0) - 1.f);
            v1 = (v1 > 0.f) ? v1 : (__expf(v1) - 1.f);
        }
        store_out(v0, v1);
        return;
    }

    const int h = lane % H;
    const int esub = lane / H;
    const float erd = er[(unsigned)(n * H) + h];

    float acc[CPT];
#pragma unroll
    for (int c = 0; c < CPT; ++c) acc[c] = 0.f;

    if (deg <= MAXCH * EPC) {
        // ================= fast path =================
        const int nch = (deg + EPC - 1) / EPC;      // wave-uniform
        int sreg[MAXCH];
        float ex[MAXCH];

#pragma unroll
        for (int j = 0; j < MAXCH; ++j)
            if (j < nch)
                sreg[j] = csr_src[beg + min(j * EPC + esub, deg - 1)];

        if constexpr (CPT == 2) {
            // -- issue el gathers first (oldest in VMEM queue) --
#pragma unroll
            for (int j = 0; j < MAXCH; ++j)
                if (j < nch) ex[j] = el[(unsigned)(sreg[j] * H) + h];

            // -- issue ALL feat-row loads (raw half2), stay outstanding --
            unsigned fraw[MAXCH][EPC];
#pragma unroll
            for (int j = 0; j < MAXCH; ++j)
                if (j < nch)
#pragma unroll
                    for (int ii = 0; ii < EPC; ++ii) {
                        int sl = __shfl(sreg[j], ii * H);
                        fraw[j][ii] = *reinterpret_cast<const unsigned*>(
                            &feat[(unsigned)(sl * D) + comp0]);
                    }

            // -- softmax under feat-load flight --
            float m = -1e30f;
#pragma unroll
            for (int j = 0; j < MAXCH; ++j) {
                if (j < nch) {
                    float v = ex[j] + erd;
                    v = (v > 0.f) ? v : 0.2f * v;   // leaky_relu 0.2
                    v = (j * EPC + esub < deg) ? v : -1e30f;
                    ex[j] = v;
                    m = fmaxf(m, v);
                }
            }
#pragma unroll
            for (int off = H; off < 64; off <<= 1)
                m = fmaxf(m, __shfl_xor(m, off));
            float s = 0.f;
#pragma unroll
            for (int j = 0; j < MAXCH; ++j) {
                if (j < nch) { ex[j] = __expf(ex[j] - m); s += ex[j]; }
            }
#pragma unroll
            for (int off = H; off < 64; off <<= 1)
                s += __shfl_xor(s, off);
            const float inv = 1.f / s;
#pragma unroll
            for (int j = 0; j < MAXCH; ++j)
                if (j < nch) ex[j] *= inv;

            // -- weighting: unpack + FMA (drains the feat queue) --
#pragma unroll
            for (int j = 0; j < MAXCH; ++j) {
                if (j < nch) {
#pragma unroll
                    for (int ii = 0; ii < EPC; ++ii) {
                        float exb = __shfl(ex[j], ii * H + myhead);
                        __half2 h2;
                        *reinterpret_cast<unsigned*>(&h2) = fraw[j][ii];
                        const float2 f = __half22float2(h2);
                        acc[0] = fmaf(f.x, exb, acc[0]);
                        acc[1] = fmaf(f.y, exb, acc[1]);
                    }
                }
            }
        } else {
            // CPT==1 (H=1, EPC=64): softmax then 2-deep ping-pong gather
#pragma unroll
            for (int j = 0; j < MAXCH; ++j)
                if (j < nch) ex[j] = el[(unsigned)(sreg[j] * H) + h];
            float m = -1e30f;
#pragma unroll
            for (int j = 0; j < MAXCH; ++j) {
                if (j < nch) {
                    float v = ex[j] + erd;
                    v = (v > 0.f) ? v : 0.2f * v;
                    v = (j * EPC + esub < deg) ? v : -1e30f;
                    ex[j] = v;
                    m = fmaxf(m, v);
                }
            }
#pragma unroll
            for (int off = H; off < 64; off <<= 1)
                m = fmaxf(m, __shfl_xor(m, off));
            float s = 0.f;
#pragma unroll
            for (int j = 0; j < MAXCH; ++j) {
                if (j < nch) { ex[j] = __expf(ex[j] - m); s += ex[j]; }
            }
#pragma unroll
            for (int off = H; off < 64; off <<= 1)
                s += __shfl_xor(s, off);
            const float inv = 1.f / s;
#pragma unroll
            for (int j = 0; j < MAXCH; ++j)
                if (j < nch) ex[j] *= inv;

            float fvA[SB], fvB[SB];
            auto ldb = [&](int j, int g, float (&fv)[SB]) {
#pragma unroll
                for (int ii = 0; ii < SB; ++ii) {
                    int sl = __shfl(sreg[j], (g + ii) * H);
                    fv[ii] = __half2float(feat[(unsigned)(sl * D) + comp0]);
                }
            };
            auto fmab = [&](int j, int g, float (&fv)[SB]) {
#pragma unroll
                for (int ii = 0; ii < SB; ++ii) {
                    float exb = __shfl(ex[j], (g + ii) * H + myhead);
                    acc[0] = fmaf(fv[ii], exb, acc[0]);
                }
            };

            ldb(0, 0, fvA);
#pragma unroll
            for (int b = 0; b < NB; ++b) {
                if (b * SB < deg) {
                    if ((b + 1) * SB < deg) {
                        const int jn = ((b + 1) * SB) / EPC;
                        const int gn = ((b + 1) * SB) % EPC;
                        if ((b & 1) == 0) ldb(jn, gn, fvB);
                        else              ldb(jn, gn, fvA);
                    }
                    const int j = (b * SB) / EPC;
                    const int g = (b * SB) % EPC;
                    if ((b & 1) == 0) fmab(j, g, fvA);
                    else              fmab(j, g, fvB);
                }
            }
        }
#pragma unroll
        for (int c = 0; c < CPT; ++c) {
            float v = acc[c] + bias[comp0 + c];
            if (ACT) v = (v > 0.f) ? v : (__expf(v) - 1.f);
            acc[c] = v;
        }
    } else {
        // ================= generic online fallback =================
        float m_run = -1e30f, s_run = 0.f;
        int sN = csr_src[beg + min(esub, deg - 1)];
        float elN = el[(unsigned)(sN * H) + h];

        for (int base = 0; base < deg; base += EPC) {
            const int s_mine = sN;
            const float elv = elN;
            const int nb = base + EPC;
            if (nb < deg) {
                sN = csr_src[beg + min(nb + esub, deg - 1)];
                elN = el[(unsigned)(sN * H) + h];
            }
            float v = elv + erd;
            v = (v > 0.f) ? v : 0.2f * v;
            float logit = (base + esub < deg) ? v : -1e30f;

            float cmax = logit;
#pragma unroll
            for (int off = H; off < 64; off <<= 1)
                cmax = fmaxf(cmax, __shfl_xor(cmax, off));
            float nm = fmaxf(m_run, cmax);
            float scale = __expf(m_run - nm);
            float ex = __expf(logit - nm);
            float csum = ex;
#pragma unroll
            for (int off = H; off < 64; off <<= 1)
                csum += __shfl_xor(csum, off);
            s_run = s_run * scale + csum;
            m_run = nm;

            const float sc = __shfl(scale, myhead);
#pragma unroll
            for (int c = 0; c < CPT; ++c) acc[c] *= sc;

            const int active = min(EPC, deg - base);
            for (int g = 0; g < active; g += SB) {
                float fv[SB][CPT];
#pragma unroll
                for (int ii = 0; ii < SB; ++ii) {
                    int sl = __shfl(s_mine, (g + ii) * H);
                    if constexpr (CPT == 2) {
                        const __half2 t = *reinterpret_cast<const __half2*>(
                            &feat[(unsigned)(sl * D) + comp0]);
                        const float2 f = __half22float2(t);
                        fv[ii][0] = f.x; fv[ii][1] = f.y;
                    } else {
                        fv[ii][0] = __half2float(feat[(unsigned)(sl * D) + comp0]);
                    }
                }
#pragma unroll
                for (int ii = 0; ii < SB; ++ii) {
                    float exb = __shfl(ex, (g + ii) * H + myhead);
#pragma unroll
                    for (int c = 0; c < CPT; ++c)
                        acc[c] = fmaf(fv[ii][c], exb, acc[c]);
                }
            }
        }
        const float invb = __shfl(1.f / s_run, myhead);
#pragma unroll
        for (int c = 0; c < CPT; ++c) {
            float v = acc[c] * invb + bias[comp0 + c];
            if (ACT) v = (v > 0.f) ? v : (__expf(v) - 1.f);
            acc[c] = v;
        }
    }

    store_out(acc[0], (CPT == 2) ? acc[1] : 0.f);
}

// ---------------------------------------------------------------------------
extern "C" void kernel_launch(void* const* d_in, const int* in_sizes, int n_in,
                              void* d_out, int out_size, void* d_ws, size_t ws_size,
                              hipStream_t stream)
{
    const float* x   = (const float*)d_in[0];
    const int*   src = (const int*)d_in[1];
    const int*   dst = (const int*)d_in[2];
    const float* W0  = (const float*)d_in[3];
    const float* al0 = (const float*)d_in[4];
    const float* ar0 = (const float*)d_in[5];
    const float* b0  = (const float*)d_in[6];
    const float* W1  = (const float*)d_in[7];
    const float* al1 = (const float*)d_in[8];
    const float* ar1 = (const float*)d_in[9];
    const float* b1  = (const float*)d_in[10];
    const float* W2  = (const float*)d_in[11];
    const float* al2 = (const float*)d_in[12];
    const float* ar2 = (const float*)d_in[13];
    const float* b2  = (const float*)d_in[14];
    float* out = (float*)d_out;

    const int N = N_NODES, E = N_EDGES;

    const size_t wp0_h = 9 * 8 * 64 * 8;
    const size_t wp1_h = 9 * 4 * 64 * 8;
    const size_t wp2_h = 5 * 4 * 64 * 8;

    __half* Wp0 = (__half*)d_ws;
    __half* Wp1 = Wp0 + wp0_h;
    __half* Wp2 = Wp1 + wp1_h;
    float* fbase = (float*)(Wp2 + wp2_h + 2048);

    __half* feat  = (__half*)fbase;               // N*128 halves
    __half* hbufh = (__half*)(fbase + (size_t)N * 64);  // N*128 halves (fp16 h)
    float* elb  = fbase + (size_t)N * 128;        // N*8
    float* erb  = elb + (size_t)N * 8;            // N*8
    int* ibase   = (int*)(erb + (size_t)N * 8);
    int* deg     = ibase;                     // N
    int* cursor  = deg + N;                   // N
    int* offs    = cursor + N;                // N+1
    int* csr_src = offs + N + 1;              // E
    int* btot    = csr_src + E;               // 64 block partials

    const int gb_rows64 = (N + 63) / 64;      // 782
    const int gb_nodes  = (N + 3) / 4;
    const int nsb       = (N + 1023) / 1024;  // 49 scan blocks
    const int gb_pz     = (8192 + N + 255) / 256;  // prepack + zero

    // ---- prepack W fragments + zero deg (fused) ----
    prepack_zero<<<gb_pz, 256, 0, stream>>>(W0, al0, ar0, W1, al1, ar1, W2, al2, ar2,
                                            Wp0, Wp1, Wp2, deg);

    // ---- degree histogram + offsets ----
    hist_deg_part<<<800, 256, 0, stream>>>(dst, deg);
    scan_partials<<<nsb, 1024, 0, stream>>>(deg, btot, N);
    scan_btot<<<1, 64, 0, stream>>>(btot, nsb);
    scan_final<<<nsb, 1024, 0, stream>>>(deg, btot, offs, cursor, N);

    // ---- layer-0 gemm || CSR fill (fused, independent) ----
    gemm0_csr<<<784 + 800, 256, 0, stream>>>(x, Wp0, feat, elb, erb, N,
                                             src, dst, cursor, csr_src);

    // ---- layer 0 aggregation ----
    node_flash_agg<8, 16, true, __half><<<gb_nodes, 256, 0, stream>>>(
        offs, csr_src, elb, erb, feat, b0, hbufh, N);

    // ---- layer 1: 128 -> 8 heads x 16, ELU ----
    gemm_attn_mfma<128, 128, 16, __half><<<gb_rows64, 256, 0, stream>>>(
        hbufh, Wp1, feat, elb, erb, N);
    node_flash_agg<8, 16, true, __half><<<gb_nodes, 256, 0, stream>>>(
        offs, csr_src, elb, erb, feat, b1, hbufh, N);

    // ---- layer 2: 128 -> 1 head x 64, no act ----
    gemm_attn_mfma<128, 64, 64, __half><<<gb_rows64, 256, 0, stream>>>(
        hbufh, Wp2, feat, elb, erb, N);
    node_flash_agg<1, 64, false, float><<<gb_nodes, 256, 0, stream>>>(
        offs, csr_src, elb, erb, feat, b2, out, N);
}

// Round 21
// 251.573 us; speedup vs baseline: 1.0779x; 1.0779x over previous
//
#include <hip/hip_runtime.h>
#include <hip/hip_bf16.h>
#include <hip/hip_fp16.h>
#include <cstdint>

#define N_NODES 50000
#define N_EDGES 800000

typedef _Float16 half8_t __attribute__((ext_vector_type(8)));
typedef float f32x4 __attribute__((ext_vector_type(4)));

// ---------------------------------------------------------------------------
// Prepack W (fp32 [DIN][DOUT]) into fp16 B-fragment order for 16x16x32 MFMA,
// plus an extra 16-col tile holding Wal/War (el/er as GEMM columns).
template<int DIN, int DOUT, int F>
__device__ __forceinline__ void prepack_body(
    const float* __restrict__ W, const float* __restrict__ al,
    const float* __restrict__ ar, __half* __restrict__ Wp, int f)
{
    constexpr int NKS = DIN / 32;
    constexpr int NT  = DOUT / 16;
    constexpr int H   = DOUT / F;
    int lane = f & 63;
    int ks   = (f >> 6) % NKS;
    int nt   = (f >> 6) / NKS;
    int kbase = ks * 32 + (lane >> 4) * 8;
    int n = lane & 15;
    __half h[8];
    if (nt < NT) {
#pragma unroll
        for (int j = 0; j < 8; ++j)
            h[j] = __float2half(W[(size_t)(kbase + j) * DOUT + nt * 16 + n]);
    } else {
#pragma unroll
        for (int j = 0; j < 8; ++j) {
            float s = 0.f;
            if (n < H) {
                for (int ff = 0; ff < F; ++ff)
                    s += W[(size_t)(kbase + j) * DOUT + n * F + ff] * al[n * F + ff];
            } else if (n < 2 * H) {
                int hh = n - H;
                for (int ff = 0; ff < F; ++ff)
                    s += W[(size_t)(kbase + j) * DOUT + hh * F + ff] * ar[hh * F + ff];
            }
            h[j] = __float2half(s);
        }
    }
    *reinterpret_cast<uint4*>(&Wp[(size_t)f * 8]) = *reinterpret_cast<uint4*>(h);
}

// prepack all 3 layers (regions 4608 | 2304 | 1280) PLUS deg zeroing (fused).
__global__ void prepack_zero(
    const float* __restrict__ W0, const float* __restrict__ al0, const float* __restrict__ ar0,
    const float* __restrict__ W1, const float* __restrict__ al1, const float* __restrict__ ar1,
    const float* __restrict__ W2, const float* __restrict__ al2, const float* __restrict__ ar2,
    __half* __restrict__ Wp0, __half* __restrict__ Wp1, __half* __restrict__ Wp2,
    int* __restrict__ deg)
{
    int f = blockIdx.x * blockDim.x + threadIdx.x;
    if (f < 4608)       prepack_body<256, 128, 16>(W0, al0, ar0, Wp0, f);
    else if (f < 6912)  prepack_body<128, 128, 16>(W1, al1, ar1, Wp1, f - 4608);
    else if (f < 8192)  prepack_body<128, 64, 64>(W2, al2, ar2, Wp2, f - 6912);
    else {
        int i = f - 8192;
        if (i < N_NODES) deg[i] = 0;
    }
}

// ---------------------------------------------------------------------------
// feat = X @ W via fp16 MFMA (fp32 accum), el/er as extra output columns.
// 1-deep X prefetch (R19-proven; R20's 16-deep burst regressed -- compiler
// rematerializes instead of keeping the burst in flight).
template<int DIN, int DOUT, int F, typename XT>
__device__ __forceinline__ void gemm_body(
    int bid, const XT* __restrict__ X, const __half* __restrict__ Wp,
    __half* __restrict__ feat, float* __restrict__ el, float* __restrict__ er, int N)
{
    constexpr int NKS = DIN / 32;
    constexpr int NT  = DOUT / 16;
    constexpr int NTT = NT + 1;         // + el/er tile
    constexpr int H   = DOUT / F;

    const int wid  = threadIdx.x >> 6;
    const int lane = threadIdx.x & 63;
    const int row0 = bid * 64 + wid * 16;
    const int m    = lane & 15;
    const int kg   = lane >> 4;

    const int rowa = min(row0 + m, N - 1);
    const XT* Xr = X + (size_t)rowa * DIN + kg * 8;

    f32x4 acc[NTT];
#pragma unroll
    for (int i = 0; i < NTT; ++i) acc[i] = (f32x4){0.f, 0.f, 0.f, 0.f};

    if constexpr (sizeof(XT) == 4) {
        float4 xa = *reinterpret_cast<const float4*>(Xr);
        float4 xb = *reinterpret_cast<const float4*>(Xr + 4);
#pragma unroll
        for (int ks = 0; ks < NKS; ++ks) {
            float4 xan = xa, xbn = xb;
            if (ks + 1 < NKS) {
                xan = *reinterpret_cast<const float4*>(Xr + (ks + 1) * 32);
                xbn = *reinterpret_cast<const float4*>(Xr + (ks + 1) * 32 + 4);
            }
            half8_t a;
            a[0] = (_Float16)xa.x; a[1] = (_Float16)xa.y;
            a[2] = (_Float16)xa.z; a[3] = (_Float16)xa.w;
            a[4] = (_Float16)xb.x; a[5] = (_Float16)xb.y;
            a[6] = (_Float16)xb.z; a[7] = (_Float16)xb.w;
#pragma unroll
            for (int nt = 0; nt < NTT; ++nt) {
                const half8_t b = *reinterpret_cast<const half8_t*>(
                    Wp + ((size_t)(nt * NKS + ks) * 64 + lane) * 8);
                acc[nt] = __builtin_amdgcn_mfma_f32_16x16x32_f16(a, b, acc[nt], 0, 0, 0);
            }
            xa = xan; xb = xbn;
        }
    } else {
        half8_t a = *reinterpret_cast<const half8_t*>(Xr);
#pragma unroll
        for (int ks = 0; ks < NKS; ++ks) {
            half8_t an = a;
            if (ks + 1 < NKS)
                an = *reinterpret_cast<const half8_t*>(Xr + (ks + 1) * 32);
#pragma unroll
            for (int nt = 0; nt < NTT; ++nt) {
                const half8_t b = *reinterpret_cast<const half8_t*>(
                    Wp + ((size_t)(nt * NKS + ks) * 64 + lane) * 8);
                acc[nt] = __builtin_amdgcn_mfma_f32_16x16x32_f16(a, b, acc[nt], 0, 0, 0);
            }
            a = an;
        }
    }

    // ---- store: C/D layout col=lane&15, row=(lane>>4)*4+reg ----
    const int q = lane >> 4;
#pragma unroll
    for (int reg = 0; reg < 4; ++reg) {
        const int row = row0 + 4 * q + reg;
        if (row < N) {
#pragma unroll
            for (int nt = 0; nt < NT; ++nt)
                feat[(size_t)row * DOUT + nt * 16 + m] = __float2half(acc[nt][reg]);
            const float v = acc[NT][reg];
            if (m < H)          el[(size_t)row * H + m] = v;
            else if (m < 2 * H) er[(size_t)row * H + (m - H)] = v;
        }
    }
}

template<int DIN, int DOUT, int F, typename XT>
__global__ __launch_bounds__(256) void gemm_attn_mfma(
    const XT* __restrict__ X, const __half* __restrict__ Wp,
    __half* __restrict__ feat, float* __restrict__ el, float* __restrict__ er, int N)
{
    gemm_body<DIN, DOUT, F, XT>(blockIdx.x, X, Wp, feat, el, er, N);
}

// ---------------------------------------------------------------------------
// dst-range-partitioned histogram body (atomics target = 200 KB deg region:
// stays L2-resident even under co-running gemm streaming).
__device__ __forceinline__ void hist_body(
    int bid, const int* __restrict__ dst, int* __restrict__ deg)
{
    constexpr int RNG = N_NODES / 8;
    constexpr int SS  = N_EDGES / 100;
    const int g  = bid & 7;
    const int s  = bid >> 3;
    const int lo = g * RNG;
    const int e0 = s * SS;
    for (int q = threadIdx.x; q < SS / 4; q += 256) {
        const int4 d = *reinterpret_cast<const int4*>(&dst[e0 + 4 * q]);
#pragma unroll
        for (int k = 0; k < 4; ++k) {
            const int dv = (k == 0) ? d.x : (k == 1) ? d.y : (k == 2) ? d.z : d.w;
            if ((unsigned)(dv - lo) < (unsigned)RNG) atomicAdd(&deg[dv], 1);
        }
    }
}

// Fused: layer-0 MFMA gemm (blocks 0..781) || degree histogram (784..1583).
// (CSR FILL is deliberately NOT fused here: R20 showed the gemm's 51 MB X
// streaming evicts the csr region between its ~16 per-line writes, restoring
// the 10x writeback amplification. hist's 200 KB target survives eviction.)
__global__ __launch_bounds__(256) void gemm0_hist(
    const float* __restrict__ X, const __half* __restrict__ Wp0,
    __half* __restrict__ feat, float* __restrict__ el, float* __restrict__ er, int N,
    const int* __restrict__ dst, int* __restrict__ deg)
{
    if (blockIdx.x < 784) {
        if (blockIdx.x < 782)
            gemm_body<256, 128, 16, float>(blockIdx.x, X, Wp0, feat, el, er, N);
    } else {
        hist_body(blockIdx.x - 784, dst, deg);
    }
}

// ---------------------------------------------------------------------------
// Multi-block scan, 3 stages.
__global__ __launch_bounds__(1024) void scan_partials(
    const int* __restrict__ deg, int* __restrict__ btot, int n)
{
    __shared__ int wsum[16];
    const int tid = threadIdx.x;
    const int lane = tid & 63, wid = tid >> 6;
    int i = blockIdx.x * 1024 + tid;
    int v = (i < n) ? deg[i] : 0;
#pragma unroll
    for (int off = 1; off < 64; off <<= 1) v += __shfl_xor(v, off);
    if (lane == 0) wsum[wid] = v;
    __syncthreads();
    if (tid < 16) {
        int w = wsum[tid];
#pragma unroll
        for (int off = 1; off < 16; off <<= 1) w += __shfl_xor(w, off, 16);
        if (tid == 0) btot[blockIdx.x] = w;
    }
}

__global__ void scan_btot(int* __restrict__ btot, int nb)
{
    int tid = threadIdx.x;          // one wave, nb <= 64
    int v = (tid < nb) ? btot[tid] : 0;
    int x = v;
#pragma unroll
    for (int off = 1; off < 64; off <<= 1) {
        int t = __shfl_up(x, off);
        if (tid >= off) x += t;
    }
    if (tid < nb) btot[tid] = x - v;    // exclusive
}

// Writes offs AND initializes cursor = offs.
__global__ __launch_bounds__(1024) void scan_final(
    const int* __restrict__ deg, const int* __restrict__ bcar,
    int* __restrict__ offs, int* __restrict__ cursor, int n)
{
    __shared__ int wtot[16], wincl[16];
    const int tid = threadIdx.x;
    const int lane = tid & 63, wid = tid >> 6;
    int i = blockIdx.x * 1024 + tid;
    int v = (i < n) ? deg[i] : 0;
    int x = v;
#pragma unroll
    for (int off = 1; off < 64; off <<= 1) {
        int t = __shfl_up(x, off);
        if (lane >= off) x += t;
    }
    if (lane == 63) wtot[wid] = x;
    __syncthreads();
    if (tid < 16) {
        int wx = wtot[tid];
#pragma unroll
        for (int off = 1; off < 16; off <<= 1) {
            int t = __shfl_up(wx, off, 16);
            if (tid >= off) wx += t;
        }
        wincl[tid] = wx;
    }
    __syncthreads();
    int waveExcl = (wid == 0) ? 0 : wincl[wid - 1];
    if (i < n) {
        int o = bcar[blockIdx.x] + waveExcl + (x - v);
        offs[i] = o;
        cursor[i] = o;
    }
    if (i == 0) offs[n] = N_EDGES;
}

// dst-range-partitioned CSR fill, STANDALONE (R16-proven: alone, the 400 KB
// per-range regions stay L2-resident -> ~1x line writeback).
__global__ __launch_bounds__(256) void build_csr_part(
    const int* __restrict__ src, const int* __restrict__ dst,
    int* __restrict__ cursor, int* __restrict__ csr_src)
{
    constexpr int RNG = N_NODES / 8;        // 6250
    constexpr int SS  = N_EDGES / 100;      // 8000 edges per slice
    const int g  = blockIdx.x & 7;
    const int s  = blockIdx.x >> 3;         // 0..99
    const int lo = g * RNG;
    const int e0 = s * SS;

    for (int q = threadIdx.x; q < SS / 4; q += 256) {
        const int4 d = *reinterpret_cast<const int4*>(&dst[e0 + 4 * q]);
#pragma unroll
        for (int k = 0; k < 4; ++k) {
            const int dv = (k == 0) ? d.x : (k == 1) ? d.y : (k == 2) ? d.z : d.w;
            const unsigned r = (unsigned)(dv - lo);
            if (r < (unsigned)RNG) {
                int sv = src[e0 + 4 * q + k];
                int p = atomicAdd(&cursor[dv], 1);
                csr_src[p] = sv;
            }
        }
    }
}

// ---------------------------------------------------------------------------
// Fused softmax + aggregation per dst node. One wave per node. fp16 feat.
template<int H, int F, bool ACT, typename OT>
__global__ __launch_bounds__(256) void node_flash_agg(
    const int* __restrict__ offs, const int* __restrict__ csr_src,
    const float* __restrict__ el, const float* __restrict__ er,
    const __half* __restrict__ feat, const float* __restrict__ bias,
    OT* __restrict__ out, int N)
{
    constexpr int D = H * F;
    constexpr int CPT = D / 64;             // 2 or 1
    constexpr int EPC = 64 / H;             // 8 or 64
    constexpr int MAXCH = (H == 8) ? 4 : 1; // fast path: deg<=32 / 64
    constexpr int SB = 8;
    constexpr int NB = MAXCH * EPC / SB;    // feat batches (4 or 8)

    const int wid = threadIdx.x >> 6;
    const int lane = threadIdx.x & 63;
    const int n = blockIdx.x * 4 + wid;
    if (n >= N) return;

    const int beg = offs[n];
    const int deg = offs[n + 1] - beg;

    const int comp0 = CPT * lane;
    const int myhead = comp0 / F;

    auto store_out = [&](float a0, float a1) {
        if constexpr (CPT == 2) {
            if constexpr (sizeof(OT) == 2) {
                *reinterpret_cast<__half2*>(&out[(size_t)n * D + comp0]) =
                    __floats2half2_rn(a0, a1);
            } else {
                *reinterpret_cast<float2*>(&out[(size_t)n * D + comp0]) =
                    make_float2(a0, a1);
            }
        } else {
            out[(size_t)n * D + comp0] = (OT)a0;
        }
    };

    if (deg == 0) {
        float v0 = bias[comp0], v1 = (CPT == 2) ? bias[comp0 + 1] : 0.f;
        if (ACT) {
            v0 = (v0 > 0.f) ? v0 : (__expf(v0) - 1.f);
            v1 = (v1 > 0.f) ? v1 : (__expf(v1) - 1.f);
        }
        store_out(v0, v1);
        return;
    }

    const int h = lane % H;
    const int esub = lane / H;
    const float erd = er[(unsigned)(n * H) + h];

    float acc[CPT];
#pragma unroll
    for (int c = 0; c < CPT; ++c) acc[c] = 0.f;

    if (deg <= MAXCH * EPC) {
        // ================= fast path =================
        const int nch = (deg + EPC - 1) / EPC;      // wave-uniform
        int sreg[MAXCH];
        float ex[MAXCH];

#pragma unroll
        for (int j = 0; j < MAXCH; ++j)
            if (j < nch)
                sreg[j] = csr_src[beg + min(j * EPC + esub, deg - 1)];

        if constexpr (CPT == 2) {
            // -- issue el gathers first (oldest in VMEM queue) --
#pragma unroll
            for (int j = 0; j < MAXCH; ++j)
                if (j < nch) ex[j] = el[(unsigned)(sreg[j] * H) + h];

            // -- issue ALL feat-row loads (raw half2), stay outstanding --
            unsigned fraw[MAXCH][EPC];
#pragma unroll
            for (int j = 0; j < MAXCH; ++j)
                if (j < nch)
#pragma unroll
                    for (int ii = 0; ii < EPC; ++ii) {
                        int sl = __shfl(sreg[j], ii * H);
                        fraw[j][ii] = *reinterpret_cast<const unsigned*>(
                            &feat[(unsigned)(sl * D) + comp0]);
                    }

            // -- softmax under feat-load flight --
            float m = -1e30f;
#pragma unroll
            for (int j = 0; j < MAXCH; ++j) {
                if (j < nch) {
                    float v = ex[j] + erd;
                    v = (v > 0.f) ? v : 0.2f * v;   // leaky_relu 0.2
                    v = (j * EPC + esub < deg) ? v : -1e30f;
                    ex[j] = v;
                    m = fmaxf(m, v);
                }
            }
#pragma unroll
            for (int off = H; off < 64; off <<= 1)
                m = fmaxf(m, __shfl_xor(m, off));
            float s = 0.f;
#pragma unroll
            for (int j = 0; j < MAXCH; ++j) {
                if (j < nch) { ex[j] = __expf(ex[j] - m); s += ex[j]; }
            }
#pragma unroll
            for (int off = H; off < 64; off <<= 1)
                s += __shfl_xor(s, off);
            const float inv = 1.f / s;
#pragma unroll
            for (int j = 0; j < MAXCH; ++j)
                if (j < nch) ex[j] *= inv;

            // -- weighting: unpack + FMA (drains the feat queue) --
#pragma unroll
            for (int j = 0; j < MAXCH; ++j) {
                if (j < nch) {
#pragma unroll
                    for (int ii = 0; ii < EPC; ++ii) {
                        float exb = __shfl(ex[j], ii * H + myhead);
                        __half2 h2;
                        *reinterpret_cast<unsigned*>(&h2) = fraw[j][ii];
                        const float2 f = __half22float2(h2);
                        acc[0] = fmaf(f.x, exb, acc[0]);
                        acc[1] = fmaf(f.y, exb, acc[1]);
                    }
                }
            }
        } else {
            // CPT==1 (H=1, EPC=64): softmax then 2-deep ping-pong gather
#pragma unroll
            for (int j = 0; j < MAXCH; ++j)
                if (j < nch) ex[j] = el[(unsigned)(sreg[j] * H) + h];
            float m = -1e30f;
#pragma unroll
            for (int j = 0; j < MAXCH; ++j) {
                if (j < nch) {
                    float v = ex[j] + erd;
                    v = (v > 0.f) ? v : 0.2f * v;
                    v = (j * EPC + esub < deg) ? v : -1e30f;
                    ex[j] = v;
                    m = fmaxf(m, v);
                }
            }
#pragma unroll
            for (int off = H; off < 64; off <<= 1)
                m = fmaxf(m, __shfl_xor(m, off));
            float s = 0.f;
#pragma unroll
            for (int j = 0; j < MAXCH; ++j) {
                if (j < nch) { ex[j] = __expf(ex[j] - m); s += ex[j]; }
            }
#pragma unroll
            for (int off = H; off < 64; off <<= 1)
                s += __shfl_xor(s, off);
            const float inv = 1.f / s;
#pragma unroll
            for (int j = 0; j < MAXCH; ++j)
                if (j < nch) ex[j] *= inv;

            float fvA[SB], fvB[SB];
            auto ldb = [&](int j, int g, float (&fv)[SB]) {
#pragma unroll
                for (int ii = 0; ii < SB; ++ii) {
                    int sl = __shfl(sreg[j], (g + ii) * H);
                    fv[ii] = __half2float(feat[(unsigned)(sl * D) + comp0]);
                }
            };
            auto fmab = [&](int j, int g, float (&fv)[SB]) {
#pragma unroll
                for (int ii = 0; ii < SB; ++ii) {
                    float exb = __shfl(ex[j], (g + ii) * H + myhead);
                    acc[0] = fmaf(fv[ii], exb, acc[0]);
                }
            };

            ldb(0, 0, fvA);
#pragma unroll
            for (int b = 0; b < NB; ++b) {
                if (b * SB < deg) {
                    if ((b + 1) * SB < deg) {
                        const int jn = ((b + 1) * SB) / EPC;
                        const int gn = ((b + 1) * SB) % EPC;
                        if ((b & 1) == 0) ldb(jn, gn, fvB);
                        else              ldb(jn, gn, fvA);
                    }
                    const int j = (b * SB) / EPC;
                    const int g = (b * SB) % EPC;
                    if ((b & 1) == 0) fmab(j, g, fvA);
                    else              fmab(j, g, fvB);
                }
            }
        }
#pragma unroll
        for (int c = 0; c < CPT; ++c) {
            float v = acc[c] + bias[comp0 + c];
            if (ACT) v = (v > 0.f) ? v : (__expf(v) - 1.f);
            acc[c] = v;
        }
    } else {
        // ================= generic online fallback =================
        float m_run = -1e30f, s_run = 0.f;
        int sN = csr_src[beg + min(esub, deg - 1)];
        float elN = el[(unsigned)(sN * H) + h];

        for (int base = 0; base < deg; base += EPC) {
            const int s_mine = sN;
            const float elv = elN;
            const int nb = base + EPC;
            if (nb < deg) {
                sN = csr_src[beg + min(nb + esub, deg - 1)];
                elN = el[(unsigned)(sN * H) + h];
            }
            float v = elv + erd;
            v = (v > 0.f) ? v : 0.2f * v;
            float logit = (base + esub < deg) ? v : -1e30f;

            float cmax = logit;
#pragma unroll
            for (int off = H; off < 64; off <<= 1)
                cmax = fmaxf(cmax, __shfl_xor(cmax, off));
            float nm = fmaxf(m_run, cmax);
            float scale = __expf(m_run - nm);
            float ex = __expf(logit - nm);
            float csum = ex;
#pragma unroll
            for (int off = H; off < 64; off <<= 1)
                csum += __shfl_xor(csum, off);
            s_run = s_run * scale + csum;
            m_run = nm;

            const float sc = __shfl(scale, myhead);
#pragma unroll
            for (int c = 0; c < CPT; ++c) acc[c] *= sc;

            const int active = min(EPC, deg - base);
            for (int g = 0; g < active; g += SB) {
                float fv[SB][CPT];
#pragma unroll
                for (int ii = 0; ii < SB; ++ii) {
                    int sl = __shfl(s_mine, (g + ii) * H);
                    if constexpr (CPT == 2) {
                        const __half2 t = *reinterpret_cast<const __half2*>(
                            &feat[(unsigned)(sl * D) + comp0]);
                        const float2 f = __half22float2(t);
                        fv[ii][0] = f.x; fv[ii][1] = f.y;
                    } else {
                        fv[ii][0] = __half2float(feat[(unsigned)(sl * D) + comp0]);
                    }
                }
#pragma unroll
                for (int ii = 0; ii < SB; ++ii) {
                    float exb = __shfl(ex, (g + ii) * H + myhead);
#pragma unroll
                    for (int c = 0; c < CPT; ++c)
                        acc[c] = fmaf(fv[ii][c], exb, acc[c]);
                }
            }
        }
        const float invb = __shfl(1.f / s_run, myhead);
#pragma unroll
        for (int c = 0; c < CPT; ++c) {
            float v = acc[c] * invb + bias[comp0 + c];
            if (ACT) v = (v > 0.f) ? v : (__expf(v) - 1.f);
            acc[c] = v;
        }
    }

    store_out(acc[0], (CPT == 2) ? acc[1] : 0.f);
}

// ---------------------------------------------------------------------------
extern "C" void kernel_launch(void* const* d_in, const int* in_sizes, int n_in,
                              void* d_out, int out_size, void* d_ws, size_t ws_size,
                              hipStream_t stream)
{
    const float* x   = (const float*)d_in[0];
    const int*   src = (const int*)d_in[1];
    const int*   dst = (const int*)d_in[2];
    const float* W0  = (const float*)d_in[3];
    const float* al0 = (const float*)d_in[4];
    const float* ar0 = (const float*)d_in[5];
    const float* b0  = (const float*)d_in[6];
    const float* W1  = (const float*)d_in[7];
    const float* al1 = (const float*)d_in[8];
    const float* ar1 = (const float*)d_in[9];
    const float* b1  = (const float*)d_in[10];
    const float* W2  = (const float*)d_in[11];
    const float* al2 = (const float*)d_in[12];
    const float* ar2 = (const float*)d_in[13];
    const float* b2  = (const float*)d_in[14];
    float* out = (float*)d_out;

    const int N = N_NODES, E = N_EDGES;

    const size_t wp0_h = 9 * 8 * 64 * 8;
    const size_t wp1_h = 9 * 4 * 64 * 8;
    const size_t wp2_h = 5 * 4 * 64 * 8;

    __half* Wp0 = (__half*)d_ws;
    __half* Wp1 = Wp0 + wp0_h;
    __half* Wp2 = Wp1 + wp1_h;
    float* fbase = (float*)(Wp2 + wp2_h + 2048);

    __half* feat  = (__half*)fbase;               // N*128 halves
    __half* hbufh = (__half*)(fbase + (size_t)N * 64);  // N*128 halves (fp16 h)
    float* elb  = fbase + (size_t)N * 128;        // N*8
    float* erb  = elb + (size_t)N * 8;            // N*8
    int* ibase   = (int*)(erb + (size_t)N * 8);
    int* deg     = ibase;                     // N
    int* cursor  = deg + N;                   // N
    int* offs    = cursor + N;                // N+1
    int* csr_src = offs + N + 1;              // E
    int* btot    = csr_src + E;               // 64 block partials

    const int gb_rows64 = (N + 63) / 64;      // 782
    const int gb_nodes  = (N + 3) / 4;
    const int nsb       = (N + 1023) / 1024;  // 49 scan blocks
    const int gb_pz     = (8192 + N + 255) / 256;  // prepack + zero

    // ---- prepack W fragments + zero deg (fused) ----
    prepack_zero<<<gb_pz, 256, 0, stream>>>(W0, al0, ar0, W1, al1, ar1, W2, al2, ar2,
                                            Wp0, Wp1, Wp2, deg);

    // ---- layer-0 gemm || degree histogram (fused; hist's 200 KB atomic
    //      target survives the gemm's streaming, unlike the csr fill) ----
    gemm0_hist<<<784 + 800, 256, 0, stream>>>(x, Wp0, feat, elb, erb, N, dst, deg);

    // ---- offsets + cursor ----
    scan_partials<<<nsb, 1024, 0, stream>>>(deg, btot, N);
    scan_btot<<<1, 64, 0, stream>>>(btot, nsb);
    scan_final<<<nsb, 1024, 0, stream>>>(deg, btot, offs, cursor, N);

    // ---- CSR fill (standalone: L2-resident regions, ~1x writeback) ----
    build_csr_part<<<800, 256, 0, stream>>>(src, dst, cursor, csr_src);

    // ---- layer 0 aggregation ----
    node_flash_agg<8, 16, true, __half><<<gb_nodes, 256, 0, stream>>>(
        offs, csr_src, elb, erb, feat, b0, hbufh, N);

    // ---- layer 1: 128 -> 8 heads x 16, ELU ----
    gemm_attn_mfma<128, 128, 16, __half><<<gb_rows64, 256, 0, stream>>>(
        hbufh, Wp1, feat, elb, erb, N);
    node_flash_agg<8, 16, true, __half><<<gb_nodes, 256, 0, stream>>>(
        offs, csr_src, elb, erb, feat, b1, hbufh, N);

    // ---- layer 2: 128 -> 1 head x 64, no act ----
    gemm_attn_mfma<128, 64, 64, __half><<<gb_rows64, 256, 0, stream>>>(
        hbufh, Wp2, feat, elb, erb, N);
    node_flash_agg<1, 64, false, float><<<gb_nodes, 256, 0, stream>>>(
        offs, csr_src, elb, erb, feat, b2, out, N);
}